// Round 4
// baseline (295.747 us; speedup 1.0000x reference)
//
#include <hip/hip_runtime.h>
#include <stdint.h>

typedef __attribute__((ext_vector_type(8))) __bf16 bf16x8;
typedef __attribute__((ext_vector_type(4))) float f32x4;
typedef unsigned short u16;
typedef unsigned char u8;
typedef unsigned int u32;
typedef unsigned long long u64;
typedef long i64;

#define LN_EPS 1e-5f

__device__ __forceinline__ float bf2f(u16 u){
  union { u32 i; float f; } v; v.i = ((u32)u) << 16; return v.f;
}
__device__ __forceinline__ u16 f2bf(float f){
  union { float f; u32 i; } v; v.f = f;
  u32 u = v.i;
  u += 0x7fffu + ((u >> 16) & 1u);
  return (u16)(u >> 16);
}
// HW packed f32x2 -> 2x OCP e4m3 bytes (low word of dst). RNE + sat@448.
__device__ __forceinline__ u32 cvt_pk_fp8(float a, float b){
  u32 pk;
  asm("v_cvt_pk_fp8_f32 %0, %1, %2" : "=v"(pk) : "v"(a), "v"(b));
  return pk;   // byte0 = fp8(a), byte1 = fp8(b)
}

// Async global->LDS DMA, 16 B per lane (dest = uniform base + lane*16).
__device__ __forceinline__ void gload_lds16(const void* g, void* l) {
  __builtin_amdgcn_global_load_lds(
      (const __attribute__((address_space(1))) void*)g,
      (__attribute__((address_space(3))) void*)l, 16, 0, 0);
}

// ---------------------------------------------------------------------------
// Kernel 0: cast X f32 -> bf16 (one shot; kills 12x redundant conversion)
// ---------------------------------------------------------------------------
__global__ void xcast_kernel(const float* __restrict__ X, u16* __restrict__ Xb) {
  int idx = (blockIdx.x * 256 + threadIdx.x) * 8;
  float4 f0 = *(const float4*)&X[idx];
  float4 f1 = *(const float4*)&X[idx + 4];
  ushort4 lo, hi;
  lo.x = f2bf(f0.x); lo.y = f2bf(f0.y); lo.z = f2bf(f0.z); lo.w = f2bf(f0.w);
  hi.x = f2bf(f1.x); hi.y = f2bf(f1.y); hi.z = f2bf(f1.z); hi.w = f2bf(f1.w);
  *(ushort4*)&Xb[idx] = lo;
  *(ushort4*)&Xb[idx + 4] = hi;
}

// ---------------------------------------------------------------------------
// Kernel 1: transpose f32 weights -> Wt[3][512][512] bf16
// ---------------------------------------------------------------------------
__global__ void transpose_w_kernel(const float* __restrict__ Wq,
                                   const float* __restrict__ Wk,
                                   const float* __restrict__ Wv,
                                   u16* __restrict__ Wt) {
  const float* W = (blockIdx.y == 0) ? Wq : ((blockIdx.y == 1) ? Wk : Wv);
  u16* o = Wt + blockIdx.y * 512 * 512;
  int idx = blockIdx.x * 256 + threadIdx.x;
  int e = idx >> 9, d = idx & 511;
  o[e * 512 + d] = f2bf(W[d * 512 + e]);
}

// ---------------------------------------------------------------------------
// Kernel 2: QKV GEMM, fully DMA-staged (global_load_lds w=16 for A and B).
// As/Bs: 128 rows x 64 B, 16B granule g of row r stored at position g^(r&3).
// Q,K out fp8; V out fp8 TRANSPOSED Vt8[512][16384].
// ---------------------------------------------------------------------------
__launch_bounds__(256, 4)
__global__ void qkv_gemm_kernel(const u16* __restrict__ Xb,
                                const u16* __restrict__ Wt,
                                u8* __restrict__ Qo,
                                u8* __restrict__ Ko,
                                u8* __restrict__ Vto8) {
  const int z = blockIdx.y;
  const u16* Wtm = Wt + z * 512 * 512;
  const int mblk = blockIdx.x & 127;
  const int nblk = blockIdx.x >> 7;
  const int m0 = mblk * 128, n0 = nblk * 128;

  __shared__ __align__(16) u8 As[128 * 64];   // 8 KB
  __shared__ __align__(16) u8 Bs[128 * 64];   // 8 KB

  const int tid = threadIdx.x;
  const int lane = tid & 63, w = tid >> 6;
  const int wr = w >> 1, wc = w & 1;
  const int lrow = lane & 15, quad = lane >> 4;

  f32x4 acc[4][4];
#pragma unroll
  for (int i = 0; i < 4; i++)
#pragma unroll
    for (int j = 0; j < 4; j++) acc[i][j] = (f32x4){0.f, 0.f, 0.f, 0.f};

  const int srow = lane >> 2;          // 0..15 within run
  const int spos = lane & 3;           // granule position 0..3

  // preload k0 = 0
#pragma unroll
  for (int r2 = 0; r2 < 2; r2++) {
    int rowb = w * 32 + r2 * 16;
    int row = rowb + srow;
    int g = spos ^ (row & 3);
    gload_lds16(&Xb[(m0 + row) * 512 + g * 8], &As[rowb * 64]);
    gload_lds16(&Wtm[(n0 + row) * 512 + g * 8], &Bs[rowb * 64]);
  }

  for (int k = 0; k < 16; k++) {
    __syncthreads();   // tile-k DMAs complete (implicit vmcnt(0))
    bf16x8 a[4], b[4];
#pragma unroll
    for (int t = 0; t < 4; t++) {
      int ra = wr * 64 + t * 16 + lrow;
      a[t] = *(const bf16x8*)&As[ra * 64 + (quad ^ (ra & 3)) * 16];
      int rb = wc * 64 + t * 16 + lrow;
      b[t] = *(const bf16x8*)&Bs[rb * 64 + (quad ^ (rb & 3)) * 16];
    }
    __syncthreads();   // all waves' fragment reads done -> safe to restage
    if (k < 15) {
      int k0n = (k + 1) * 32;
#pragma unroll
      for (int r2 = 0; r2 < 2; r2++) {
        int rowb = w * 32 + r2 * 16;
        int row = rowb + srow;
        int g = spos ^ (row & 3);
        gload_lds16(&Xb[(m0 + row) * 512 + k0n + g * 8], &As[rowb * 64]);
        gload_lds16(&Wtm[(n0 + row) * 512 + k0n + g * 8], &Bs[rowb * 64]);
      }
    }
#pragma unroll
    for (int i = 0; i < 4; i++)
#pragma unroll
      for (int j = 0; j < 4; j++)
        acc[i][j] = __builtin_amdgcn_mfma_f32_16x16x32_bf16(a[i], b[j], acc[i][j], 0, 0, 0);
  }

  if (z < 2) {
    u8* O = (z == 0) ? Qo : Ko;
#pragma unroll
    for (int i = 0; i < 4; i++) {
      int rbase = m0 + wr * 64 + i * 16 + quad * 4;
#pragma unroll
      for (int j = 0; j < 4; j++) {
        int col = n0 + wc * 64 + j * 16 + lrow;
        u32 pk01 = cvt_pk_fp8(acc[i][j][0], acc[i][j][1]);
        u32 pk23 = cvt_pk_fp8(acc[i][j][2], acc[i][j][3]);
        O[(rbase + 0) * 512 + col] = (u8)pk01;
        O[(rbase + 1) * 512 + col] = (u8)(pk01 >> 8);
        O[(rbase + 2) * 512 + col] = (u8)pk23;
        O[(rbase + 3) * 512 + col] = (u8)(pk23 >> 8);
      }
    }
  } else {
#pragma unroll
    for (int i = 0; i < 4; i++) {
      int rbase = m0 + wr * 64 + i * 16 + quad * 4;
#pragma unroll
      for (int j = 0; j < 4; j++) {
        int col = n0 + wc * 64 + j * 16 + lrow;
        u32 pk01 = cvt_pk_fp8(acc[i][j][0], acc[i][j][1]);
        u32 pk23 = cvt_pk_fp8(acc[i][j][2], acc[i][j][3]);
        u32 pk = (pk01 & 0xffffu) | (pk23 << 16);
        *(u32*)&Vto8[col * 16384 + rbase] = pk;
      }
    }
  }
}

// ---------------------------------------------------------------------------
// Kernel 3: flash attention partial — wave-private rows, swapped-operand QK.
//
// r3 lesson: occupancy is register-pinned at 2 waves/SIMD (VGPR 120 + 128
// AGPR accumulator ~ 248 unified regs); more grid doesn't help.  So remove
// per-iteration stall instead:
//   * S^T = mfma(K, Q)  (A/B frags have identical per-lane layout, so the
//     same qf/k registers work swapped).  Output: col=q=lane&15,
//     row=key=quad*4+reg -> each lane owns 8 keys of ONE q-row.
//   * Softmax fully lane-local (scalar lsum).  P packed to fp8 dwords in
//     registers; 4 __shfl + 2 selects repack to the PV A-fragment.
//     -> NO P LDS buffer, NO second barrier, no byte-store bank conflicts.
//   * PV: 32x mfma_16x16x32_fp8 per wave (same FLOP as before), V block-shared.
//   * K/V double-buffered (64 KB LDS), staged right after the single
//     __syncthreads() -> full-iteration (~2500 cy) latency cover.
// Per-wave outputs: wave w owns q-rows w*16..w*16+15 (full 512 d).
// ---------------------------------------------------------------------------
template <int NSPLIT>
__launch_bounds__(256, 2)
__global__ void attn_partial_kernel(const u8* __restrict__ Q,
                                    const u8* __restrict__ K,
                                    const u8* __restrict__ Vt8,
                                    u16* __restrict__ Opart,  // [NSPLIT][16384][512]
                                    float* __restrict__ L) {  // [NSPLIT][16384]
  constexpr int SPAN = 4096 / NSPLIT;   // keys per split
  constexpr int ITERS = SPAN / 32;      // 32-key tiles
  const int b = blockIdx.y;
  const int split = blockIdx.z;
  const int q0 = blockIdx.x * 64;
  const int tid = threadIdx.x;
  const int lane = tid & 63, w = tid >> 6;
  const int lrow = lane & 15, quad = lane >> 4;

  __shared__ __align__(16) u8 Ks8[2][32 * 512];  // fp8, granule swz g^(row&7)
  __shared__ __align__(16) u8 Vs8[2][512 * 32];  // fp8, granule16 g^((n>>2)&1)

  const int keybase = b * 4096 + split * SPAN;

  // Q fragments: q-row = w*16+lrow, d-slice quad*8 within each 32-chunk.
  const int qtok = b * 4096 + q0 + w * 16 + lrow;
  i64 qf[16];
#pragma unroll
  for (int s = 0; s < 16; s++)
    qf[s] = *(const i64*)&Q[qtok * 512 + s * 32 + quad * 8];

  f32x4 Oacc[32];
#pragma unroll
  for (int j = 0; j < 32; j++) Oacc[j] = (f32x4){0.f, 0.f, 0.f, 0.f};

  float lsum = 0.f;
  const float scale = 0.044194173824159216f;  // 1/sqrt(512)

  auto stageK = [&](int kk, u8* Kbuf) {
#pragma unroll
    for (int i = 0; i < 4; i++) {
      int row = w * 8 + i * 2 + (lane >> 5);
      int g = (lane & 31) ^ (row & 7);
      gload_lds16(&K[(keybase + kk + row) * 512 + g * 16],
                  &Kbuf[(w * 8 + i * 2) * 512]);
    }
  };
  auto stageV = [&](int kk, u8* Vbuf) {
#pragma unroll
    for (int run = 0; run < 4; run++) {
      int rowb = w * 128 + run * 32;
      int n = rowb + (lane >> 1);
      int g16 = (lane & 1) ^ ((n >> 2) & 1);
      gload_lds16(&Vt8[n * 16384 + keybase + kk + g16 * 16], &Vbuf[rowb * 32]);
    }
  };

  stageK(0, Ks8[0]);
  stageV(0, Vs8[0]);

  for (int it = 0; it < ITERS; ++it) {
    const int cur = it & 1;
    const u8* Ksc = Ks8[cur];
    const u8* Vsc = Vs8[cur];

    // Single rendezvous: tile-it DMAs landed (implicit vmcnt(0)); every wave
    // finished iter it-1, so buf[cur^1] is free to restage.
    __syncthreads();
    if (it < ITERS - 1) {
      stageK((it + 1) * 32, Ks8[cur ^ 1]);
      stageV((it + 1) * 32, Vs8[cur ^ 1]);
    }

    // ---- QK^T, swapped operands: S^T[key][q] ----
    f32x4 S0 = {0.f, 0.f, 0.f, 0.f}, S1 = {0.f, 0.f, 0.f, 0.f};
#pragma unroll
    for (int s = 0; s < 16; s++) {
      int gs = (2 * s + (quad >> 1)) ^ (lrow & 7);
      int off = gs * 16 + (quad & 1) * 8;
      i64 k0 = *(const i64*)&Ksc[lrow * 512 + off];
      i64 k1 = *(const i64*)&Ksc[(16 + lrow) * 512 + off];
      S0 = __builtin_amdgcn_mfma_f32_16x16x32_fp8_fp8(k0, qf[s], S0, 0, 0, 0);
      S1 = __builtin_amdgcn_mfma_f32_16x16x32_fp8_fp8(k1, qf[s], S1, 0, 0, 0);
    }
    // lane(lrow,quad): S0[r] = S^T[key=quad*4+r][q=lrow], S1: key=16+quad*4+r.

    // ---- fixed-max softmax, fully in-register ----
    float p00 = __expf(S0[0] * scale), p01 = __expf(S0[1] * scale);
    float p02 = __expf(S0[2] * scale), p03 = __expf(S0[3] * scale);
    float p10 = __expf(S1[0] * scale), p11 = __expf(S1[1] * scale);
    float p12 = __expf(S1[2] * scale), p13 = __expf(S1[3] * scale);
    lsum += ((p00 + p01) + (p02 + p03)) + ((p10 + p11) + (p12 + p13));
    u32 dwA = (cvt_pk_fp8(p00, p01) & 0xffffu) | (cvt_pk_fp8(p02, p03) << 16);
    u32 dwB = (cvt_pk_fp8(p10, p11) & 0xffffu) | (cvt_pk_fp8(p12, p13) << 16);
    // dwA bytes r = P[q=lrow][key=quad*4+r]; dwB: key=16+quad*4+r.

    // ---- repack to PV A-fragment: lane needs keys quad*8..quad*8+7 of its
    // own q-row.  lo dword from srcq=2*(quad&1), hi from srcq+1; keys<16
    // (quad<2) come from dwA, keys>=16 from dwB.
    {
      int srcl = lrow + 32 * (quad & 1);
      u32 loA = (u32)__shfl((int)dwA, srcl);
      u32 hiA = (u32)__shfl((int)dwA, srcl + 16);
      u32 loB = (u32)__shfl((int)dwB, srcl);
      u32 hiB = (u32)__shfl((int)dwB, srcl + 16);
      u32 lo = (quad >= 2) ? loB : loA;
      u32 hi = (quad >= 2) ? hiB : hiA;
      i64 af = (i64)(((u64)hi << 32) | (u64)lo);

      // ---- PV: O[q 16][d 512] per wave, 32x 16x16x32 fp8 MFMA ----
#pragma unroll
      for (int j = 0; j < 32; j++) {
        int n = j * 16 + lrow;
        int off = (((quad >> 1) ^ ((n >> 2) & 1)) << 4) + (quad & 1) * 8;
        i64 bv = *(const i64*)&Vsc[n * 32 + off];
        Oacc[j] = __builtin_amdgcn_mfma_f32_16x16x32_fp8_fp8(af, bv, Oacc[j], 0, 0, 0);
      }
    }
  }

  // ---- l: reduce across the 4 quads holding the same q-row ----
  {
    float s = lsum;
    s += __shfl_xor(s, 16);
    s += __shfl_xor(s, 32);
    if (quad == 0)
      L[split * 16384 + b * 4096 + q0 + w * 16 + lrow] = s;
  }

  // ---- store unnormalized O partial, bf16 (16x16 C-layout per j-tile) ----
  u16* Ob = Opart + (size_t)split * (16384u * 512u);
  const int tokr = b * 4096 + q0 + w * 16 + quad * 4;
#pragma unroll
  for (int j = 0; j < 32; j++) {
#pragma unroll
    for (int p = 0; p < 4; p++)
      Ob[(size_t)(tokr + p) * 512 + j * 16 + lrow] = f2bf(Oacc[j][p]);
  }
}

// ---------------------------------------------------------------------------
// Kernel 4: combine splits + residual + LayerNorm.  One wave per token.
// ---------------------------------------------------------------------------
template <int NSPLIT>
__launch_bounds__(256)
__global__ void combine_ln_kernel(const u16* __restrict__ Opart,
                                  const float* __restrict__ L,
                                  const float* __restrict__ X,
                                  const float* __restrict__ gamma,
                                  const float* __restrict__ beta,
                                  float* __restrict__ Out) {
  const int lane = threadIdx.x & 63;
  const int tok = blockIdx.x * 4 + (threadIdx.x >> 6);
  float lt = 0.f;
#pragma unroll
  for (int s = 0; s < NSPLIT; s++) lt += L[s * 16384 + tok];
  const float inv_l = 1.f / lt;
  const int base = tok * 512 + lane * 8;

  float h[8] = {0.f, 0.f, 0.f, 0.f, 0.f, 0.f, 0.f, 0.f};
#pragma unroll
  for (int s = 0; s < NSPLIT; s++) {
    uint4 avec = *(const uint4*)&Opart[(size_t)s * (16384u * 512u) + base];
    const u16* ap = (const u16*)&avec;
#pragma unroll
    for (int i = 0; i < 8; i++) h[i] += bf2f(ap[i]);
  }

  float4 x0 = *(const float4*)&X[base];
  float4 x1 = *(const float4*)&X[base + 4];
  float xs[8] = {x0.x, x0.y, x0.z, x0.w, x1.x, x1.y, x1.z, x1.w};
#pragma unroll
  for (int i = 0; i < 8; i++) h[i] = h[i] * inv_l + xs[i];

  float sum = 0.f, sq = 0.f;
#pragma unroll
  for (int i = 0; i < 8; i++) { sum += h[i]; sq += h[i] * h[i]; }
#pragma unroll
  for (int d = 1; d < 64; d <<= 1) {
    sum += __shfl_xor(sum, d);
    sq  += __shfl_xor(sq, d);
  }
  float mu = sum * (1.f / 512.f);
  float var = sq * (1.f / 512.f) - mu * mu;
  float rstd = rsqrtf(var + LN_EPS);

  float4 g0 = *(const float4*)&gamma[lane * 8];
  float4 g1 = *(const float4*)&gamma[lane * 8 + 4];
  float4 b0 = *(const float4*)&beta[lane * 8];
  float4 b1 = *(const float4*)&beta[lane * 8 + 4];
  float gs[8] = {g0.x, g0.y, g0.z, g0.w, g1.x, g1.y, g1.z, g1.w};
  float bs[8] = {b0.x, b0.y, b0.z, b0.w, b1.x, b1.y, b1.z, b1.w};

  float4 o0, o1;
  float* op = (float*)&o0;
#pragma unroll
  for (int i = 0; i < 4; i++) op[i] = (h[i] - mu) * rstd * gs[i] + bs[i];
  float* op1 = (float*)&o1;
#pragma unroll
  for (int i = 0; i < 4; i++) op1[i] = (h[i + 4] - mu) * rstd * gs[i + 4] + bs[i + 4];
  *(float4*)&Out[base] = o0;
  *(float4*)&Out[base + 4] = o1;
}

// ---------------------------------------------------------------------------
extern "C" void kernel_launch(void* const* d_in, const int* in_sizes, int n_in,
                              void* d_out, int out_size, void* d_ws, size_t ws_size,
                              hipStream_t stream) {
  const float* x = (const float*)d_in[0];
  const float* Wq = (const float*)d_in[1];
  const float* Wk = (const float*)d_in[2];
  const float* Wv = (const float*)d_in[3];
  const float* gamma = (const float*)d_in[4];
  const float* beta = (const float*)d_in[5];

  char* ws = (char*)d_ws;
  u8*  Qws   = (u8*)(ws);                     // 8 MB fp8
  u8*  Kws   = (u8*)(ws + 8388608);           // 8 MB fp8
  u8*  Vt8ws = (u8*)(ws + 16777216);          // 8 MB fp8, [512][16384]
  u16* Wtws  = (u16*)(ws + 25165824);         // 1.5 MB bf16
  u16* Xbws  = (u16*)(ws + 26738688);         // 16 MB bf16 (dead after GEMM)
  u16* Opws  = (u16*)(ws + 26738688);         // 2 x 16 MB bf16 partials;
                                              //   slice 0 aliases Xb (safe:
                                              //   attn writes after gemm reads)
  const size_t PART = 16777216;
  float* Lws = (float*)(ws + 26738688 + 2 * PART);

  hipLaunchKernelGGL(xcast_kernel, dim3(4096), dim3(256), 0, stream, x, Xbws);
  hipLaunchKernelGGL(transpose_w_kernel, dim3(1024, 3), dim3(256), 0, stream,
                     Wq, Wk, Wv, Wtws);
  hipLaunchKernelGGL(qkv_gemm_kernel, dim3(512, 3), dim3(256), 0, stream,
                     Xbws, Wtws, Qws, Kws, Vt8ws);
  hipLaunchKernelGGL(HIP_KERNEL_NAME(attn_partial_kernel<2>),
                     dim3(64, 4, 2), dim3(256), 0, stream,
                     Qws, Kws, Vt8ws, Opws, Lws);
  hipLaunchKernelGGL(HIP_KERNEL_NAME(combine_ln_kernel<2>),
                     dim3(4096), dim3(256), 0, stream,
                     Opws, Lws, x, gamma, beta, (float*)d_out);
}

// Round 5
// 287.172 us; speedup vs baseline: 1.0299x; 1.0299x over previous
//
#include <hip/hip_runtime.h>
#include <stdint.h>

typedef __attribute__((ext_vector_type(8))) __bf16 bf16x8;
typedef __attribute__((ext_vector_type(4))) float f32x4;
typedef unsigned short u16;
typedef unsigned char u8;
typedef unsigned int u32;
typedef unsigned long long u64;
typedef long i64;

#define LN_EPS 1e-5f

__device__ __forceinline__ float bf2f(u16 u){
  union { u32 i; float f; } v; v.i = ((u32)u) << 16; return v.f;
}
__device__ __forceinline__ u16 f2bf(float f){
  union { float f; u32 i; } v; v.f = f;
  u32 u = v.i;
  u += 0x7fffu + ((u >> 16) & 1u);
  return (u16)(u >> 16);
}
// HW packed f32x2 -> 2x OCP e4m3 bytes (low word of dst). RNE + sat@448.
__device__ __forceinline__ u32 cvt_pk_fp8(float a, float b){
  u32 pk;
  asm("v_cvt_pk_fp8_f32 %0, %1, %2" : "=v"(pk) : "v"(a), "v"(b));
  return pk;   // byte0 = fp8(a), byte1 = fp8(b)
}

// Async global->LDS DMA, 16 B per lane (dest = uniform base + lane*16).
__device__ __forceinline__ void gload_lds16(const void* g, void* l) {
  __builtin_amdgcn_global_load_lds(
      (const __attribute__((address_space(1))) void*)g,
      (__attribute__((address_space(3))) void*)l, 16, 0, 0);
}

// ---------------------------------------------------------------------------
// Kernel 0: cast X f32 -> bf16 (one shot; kills 12x redundant conversion)
// ---------------------------------------------------------------------------
__global__ void xcast_kernel(const float* __restrict__ X, u16* __restrict__ Xb) {
  int idx = (blockIdx.x * 256 + threadIdx.x) * 8;
  float4 f0 = *(const float4*)&X[idx];
  float4 f1 = *(const float4*)&X[idx + 4];
  ushort4 lo, hi;
  lo.x = f2bf(f0.x); lo.y = f2bf(f0.y); lo.z = f2bf(f0.z); lo.w = f2bf(f0.w);
  hi.x = f2bf(f1.x); hi.y = f2bf(f1.y); hi.z = f2bf(f1.z); hi.w = f2bf(f1.w);
  *(ushort4*)&Xb[idx] = lo;
  *(ushort4*)&Xb[idx + 4] = hi;
}

// ---------------------------------------------------------------------------
// Kernel 1: transpose f32 weights -> Wt[3][512][512] bf16
// ---------------------------------------------------------------------------
__global__ void transpose_w_kernel(const float* __restrict__ Wq,
                                   const float* __restrict__ Wk,
                                   const float* __restrict__ Wv,
                                   u16* __restrict__ Wt) {
  const float* W = (blockIdx.y == 0) ? Wq : ((blockIdx.y == 1) ? Wk : Wv);
  u16* o = Wt + blockIdx.y * 512 * 512;
  int idx = blockIdx.x * 256 + threadIdx.x;
  int e = idx >> 9, d = idx & 511;
  o[e * 512 + d] = f2bf(W[d * 512 + e]);
}

// ---------------------------------------------------------------------------
// Kernel 2: QKV GEMM, fully DMA-staged (global_load_lds w=16 for A and B).
// As/Bs: 128 rows x 64 B, 16B granule g of row r stored at position g^(r&3).
// Q,K out fp8; V out fp8 TRANSPOSED Vt8[512][16384].
// ---------------------------------------------------------------------------
__launch_bounds__(256, 4)
__global__ void qkv_gemm_kernel(const u16* __restrict__ Xb,
                                const u16* __restrict__ Wt,
                                u8* __restrict__ Qo,
                                u8* __restrict__ Ko,
                                u8* __restrict__ Vto8) {
  const int z = blockIdx.y;
  const u16* Wtm = Wt + z * 512 * 512;
  const int mblk = blockIdx.x & 127;
  const int nblk = blockIdx.x >> 7;
  const int m0 = mblk * 128, n0 = nblk * 128;

  __shared__ __align__(16) u8 As[128 * 64];   // 8 KB
  __shared__ __align__(16) u8 Bs[128 * 64];   // 8 KB

  const int tid = threadIdx.x;
  const int lane = tid & 63, w = tid >> 6;
  const int wr = w >> 1, wc = w & 1;
  const int lrow = lane & 15, quad = lane >> 4;

  f32x4 acc[4][4];
#pragma unroll
  for (int i = 0; i < 4; i++)
#pragma unroll
    for (int j = 0; j < 4; j++) acc[i][j] = (f32x4){0.f, 0.f, 0.f, 0.f};

  const int srow = lane >> 2;          // 0..15 within run
  const int spos = lane & 3;           // granule position 0..3

  // preload k0 = 0
#pragma unroll
  for (int r2 = 0; r2 < 2; r2++) {
    int rowb = w * 32 + r2 * 16;
    int row = rowb + srow;
    int g = spos ^ (row & 3);
    gload_lds16(&Xb[(m0 + row) * 512 + g * 8], &As[rowb * 64]);
    gload_lds16(&Wtm[(n0 + row) * 512 + g * 8], &Bs[rowb * 64]);
  }

  for (int k = 0; k < 16; k++) {
    __syncthreads();   // tile-k DMAs complete (implicit vmcnt(0))
    bf16x8 a[4], b[4];
#pragma unroll
    for (int t = 0; t < 4; t++) {
      int ra = wr * 64 + t * 16 + lrow;
      a[t] = *(const bf16x8*)&As[ra * 64 + (quad ^ (ra & 3)) * 16];
      int rb = wc * 64 + t * 16 + lrow;
      b[t] = *(const bf16x8*)&Bs[rb * 64 + (quad ^ (rb & 3)) * 16];
    }
    __syncthreads();   // all waves' fragment reads done -> safe to restage
    if (k < 15) {
      int k0n = (k + 1) * 32;
#pragma unroll
      for (int r2 = 0; r2 < 2; r2++) {
        int rowb = w * 32 + r2 * 16;
        int row = rowb + srow;
        int g = spos ^ (row & 3);
        gload_lds16(&Xb[(m0 + row) * 512 + k0n + g * 8], &As[rowb * 64]);
        gload_lds16(&Wtm[(n0 + row) * 512 + k0n + g * 8], &Bs[rowb * 64]);
      }
    }
#pragma unroll
    for (int i = 0; i < 4; i++)
#pragma unroll
      for (int j = 0; j < 4; j++)
        acc[i][j] = __builtin_amdgcn_mfma_f32_16x16x32_bf16(a[i], b[j], acc[i][j], 0, 0, 0);
  }

  if (z < 2) {
    u8* O = (z == 0) ? Qo : Ko;
#pragma unroll
    for (int i = 0; i < 4; i++) {
      int rbase = m0 + wr * 64 + i * 16 + quad * 4;
#pragma unroll
      for (int j = 0; j < 4; j++) {
        int col = n0 + wc * 64 + j * 16 + lrow;
        u32 pk01 = cvt_pk_fp8(acc[i][j][0], acc[i][j][1]);
        u32 pk23 = cvt_pk_fp8(acc[i][j][2], acc[i][j][3]);
        O[(rbase + 0) * 512 + col] = (u8)pk01;
        O[(rbase + 1) * 512 + col] = (u8)(pk01 >> 8);
        O[(rbase + 2) * 512 + col] = (u8)pk23;
        O[(rbase + 3) * 512 + col] = (u8)(pk23 >> 8);
      }
    }
  } else {
#pragma unroll
    for (int i = 0; i < 4; i++) {
      int rbase = m0 + wr * 64 + i * 16 + quad * 4;
#pragma unroll
      for (int j = 0; j < 4; j++) {
        int col = n0 + wc * 64 + j * 16 + lrow;
        u32 pk01 = cvt_pk_fp8(acc[i][j][0], acc[i][j][1]);
        u32 pk23 = cvt_pk_fp8(acc[i][j][2], acc[i][j][3]);
        u32 pk = (pk01 & 0xffffu) | (pk23 << 16);
        *(u32*)&Vto8[col * 16384 + rbase] = pk;
      }
    }
  }
}

// ---------------------------------------------------------------------------
// Kernel 3: flash attention partial, fp8 MFMA, LDS-traffic-minimized.
//
// r4 post-mortem: kernel is LDS-BW-bound (256 KB LDS reads per CU-tile:
// every wave read full K and full V because it owned 16 q x 512 d).
// Fix: 32-q-row waves with split roles -> every K-frag and V-frag read
// feeds TWO q-group MFMAs (LDS reads/wave/tile 64 -> 34 b64):
//   wave w = (qp = w>>1, x = w&1)
//   QK:  S[keys x*16..+15][q qp*32..+31]   (K reads halved; Q regs 64)
//   PV:  O[q qp*32..+31][d x*256..+255]    (V reads halved; Oacc still 128)
//   P exchange via tiny LDS buffer Pb[64 q][stride 40] fp8 (2.5 KB).
// K/V double-buffered (66.5 KB LDS total, 2 blocks/CU), staged right after
// barrier A. Softmax stays lane-local (swapped-operand QK).
// ---------------------------------------------------------------------------
template <int NSPLIT>
__launch_bounds__(256, 2)
__global__ void attn_partial_kernel(const u8* __restrict__ Q,
                                    const u8* __restrict__ K,
                                    const u8* __restrict__ Vt8,
                                    u16* __restrict__ Opart,  // [NSPLIT][16384][512]
                                    float* __restrict__ L) {  // [2*NSPLIT][16384]
  constexpr int SPAN = 4096 / NSPLIT;   // keys per split
  constexpr int ITERS = SPAN / 32;      // 32-key tiles
  const int b = blockIdx.y;
  const int split = blockIdx.z;
  const int q0 = blockIdx.x * 64;
  const int tid = threadIdx.x;
  const int lane = tid & 63, w = tid >> 6;
  const int lrow = lane & 15, quad = lane >> 4;
  const int qp = w >> 1, x = w & 1;

  __shared__ __align__(16) u8 Ks8[2][32 * 512];  // fp8, granule swz g^(row&7)
  __shared__ __align__(16) u8 Vs8[2][512 * 32];  // fp8, granule16 g^((n>>2)&1)
  __shared__ __align__(16) u8 Pb[64 * 40];       // fp8 P[64 q][32 k], stride 40

  const int keybase = b * 4096 + split * SPAN;

  // Q fragments: 2 q-groups (qp*32+qg*16+lrow) x 16 d-steps, 8 B each.
  const int qtokb = b * 4096 + q0 + qp * 32;
  i64 qf[2][16];
#pragma unroll
  for (int qg = 0; qg < 2; qg++)
#pragma unroll
    for (int s = 0; s < 16; s++)
      qf[qg][s] = *(const i64*)&Q[(qtokb + qg * 16 + lrow) * 512 + s * 32 + quad * 8];

  f32x4 Oacc[2][16];   // [qg][j]: O[qp*32+qg*16+quad*4+r][x*256+j*16+lrow]
#pragma unroll
  for (int qg = 0; qg < 2; qg++)
#pragma unroll
    for (int j = 0; j < 16; j++) Oacc[qg][j] = (f32x4){0.f, 0.f, 0.f, 0.f};

  float lsum[2] = {0.f, 0.f};
  const float scale = 0.044194173824159216f;  // 1/sqrt(512)

  auto stageK = [&](int kk, u8* Kbuf) {
#pragma unroll
    for (int i = 0; i < 4; i++) {
      int row = w * 8 + i * 2 + (lane >> 5);
      int g = (lane & 31) ^ (row & 7);
      gload_lds16(&K[(keybase + kk + row) * 512 + g * 16],
                  &Kbuf[(w * 8 + i * 2) * 512]);
    }
  };
  auto stageV = [&](int kk, u8* Vbuf) {
#pragma unroll
    for (int run = 0; run < 4; run++) {
      int rowb = w * 128 + run * 32;
      int n = rowb + (lane >> 1);
      int g16 = (lane & 1) ^ ((n >> 2) & 1);
      gload_lds16(&Vt8[n * 16384 + keybase + kk + g16 * 16], &Vbuf[rowb * 32]);
    }
  };

  stageK(0, Ks8[0]);
  stageV(0, Vs8[0]);

  const int krow = x * 16 + lrow;   // this wave's QK key row

  for (int it = 0; it < ITERS; ++it) {
    const int cur = it & 1;
    const u8* Ksc = Ks8[cur];
    const u8* Vsc = Vs8[cur];

    __syncthreads();   // A: K/V(it) staged by all; PV(it-1) done -> Pb free,
                       //    buf[cur^1] reads complete -> restage it now.
    if (it < ITERS - 1) {
      stageK((it + 1) * 32, Ks8[cur ^ 1]);
      stageV((it + 1) * 32, Vs8[cur ^ 1]);
    }

    // ---- QK^T swapped: S[key = x*16+quad*4+r][q = qp*32+qg*16+lrow] ----
    f32x4 S0 = {0.f, 0.f, 0.f, 0.f}, S1 = {0.f, 0.f, 0.f, 0.f};
#pragma unroll
    for (int s = 0; s < 16; s++) {
      int gs = (2 * s + (quad >> 1)) ^ (krow & 7);
      int off = gs * 16 + (quad & 1) * 8;
      i64 kf = *(const i64*)&Ksc[krow * 512 + off];
      S0 = __builtin_amdgcn_mfma_f32_16x16x32_fp8_fp8(kf, qf[0][s], S0, 0, 0, 0);
      S1 = __builtin_amdgcn_mfma_f32_16x16x32_fp8_fp8(kf, qf[1][s], S1, 0, 0, 0);
    }

    // ---- fixed-max softmax (lane-local) + pack P dword, store to Pb ----
    {
      float p0 = __expf(S0[0] * scale), p1 = __expf(S0[1] * scale);
      float p2 = __expf(S0[2] * scale), p3 = __expf(S0[3] * scale);
      lsum[0] += (p0 + p1) + (p2 + p3);
      u32 dw = (cvt_pk_fp8(p0, p1) & 0xffffu) | (cvt_pk_fp8(p2, p3) << 16);
      *(u32*)&Pb[(qp * 32 + lrow) * 40 + x * 16 + quad * 4] = dw;
    }
    {
      float p0 = __expf(S1[0] * scale), p1 = __expf(S1[1] * scale);
      float p2 = __expf(S1[2] * scale), p3 = __expf(S1[3] * scale);
      lsum[1] += (p0 + p1) + (p2 + p3);
      u32 dw = (cvt_pk_fp8(p0, p1) & 0xffffu) | (cvt_pk_fp8(p2, p3) << 16);
      *(u32*)&Pb[(qp * 32 + 16 + lrow) * 40 + x * 16 + quad * 4] = dw;
    }

    __syncthreads();   // B: P visible to the whole block

    // ---- PV: A-frags (P) read once, each V-frag feeds 2 MFMAs ----
    i64 pa0 = *(const i64*)&Pb[(qp * 32 + lrow) * 40 + quad * 8];
    i64 pa1 = *(const i64*)&Pb[(qp * 32 + 16 + lrow) * 40 + quad * 8];
#pragma unroll
    for (int j = 0; j < 16; j++) {
      int n = x * 256 + j * 16 + lrow;
      int off = (((quad >> 1) ^ ((n >> 2) & 1)) << 4) + (quad & 1) * 8;
      i64 bv = *(const i64*)&Vsc[n * 32 + off];
      Oacc[0][j] = __builtin_amdgcn_mfma_f32_16x16x32_fp8_fp8(pa0, bv, Oacc[0][j], 0, 0, 0);
      Oacc[1][j] = __builtin_amdgcn_mfma_f32_16x16x32_fp8_fp8(pa1, bv, Oacc[1][j], 0, 0, 0);
    }
  }

  // ---- l: reduce across quads (keys) per qg, store per key-half slot ----
#pragma unroll
  for (int qg = 0; qg < 2; qg++) {
    float s = lsum[qg];
    s += __shfl_xor(s, 16);
    s += __shfl_xor(s, 32);
    if (quad == 0)
      L[(split * 2 + x) * 16384 + b * 4096 + q0 + qp * 32 + qg * 16 + lrow] = s;
  }

  // ---- store unnormalized O partial, bf16 ----
  u16* Ob = Opart + (size_t)split * (16384u * 512u);
  const int tokb2 = b * 4096 + q0 + qp * 32;
#pragma unroll
  for (int qg = 0; qg < 2; qg++)
#pragma unroll
    for (int j = 0; j < 16; j++) {
      int col = x * 256 + j * 16 + lrow;
#pragma unroll
      for (int r = 0; r < 4; r++)
        Ob[(size_t)(tokb2 + qg * 16 + quad * 4 + r) * 512 + col] = f2bf(Oacc[qg][j][r]);
    }
}

// ---------------------------------------------------------------------------
// Kernel 4: combine splits + residual + LayerNorm.  One wave per token.
// L has 2*NSPLIT slots (per split x per key-half).
// ---------------------------------------------------------------------------
template <int NSPLIT>
__launch_bounds__(256)
__global__ void combine_ln_kernel(const u16* __restrict__ Opart,
                                  const float* __restrict__ L,
                                  const float* __restrict__ X,
                                  const float* __restrict__ gamma,
                                  const float* __restrict__ beta,
                                  float* __restrict__ Out) {
  const int lane = threadIdx.x & 63;
  const int tok = blockIdx.x * 4 + (threadIdx.x >> 6);
  float lt = 0.f;
#pragma unroll
  for (int s = 0; s < 2 * NSPLIT; s++) lt += L[s * 16384 + tok];
  const float inv_l = 1.f / lt;
  const int base = tok * 512 + lane * 8;

  float h[8] = {0.f, 0.f, 0.f, 0.f, 0.f, 0.f, 0.f, 0.f};
#pragma unroll
  for (int s = 0; s < NSPLIT; s++) {
    uint4 avec = *(const uint4*)&Opart[(size_t)s * (16384u * 512u) + base];
    const u16* ap = (const u16*)&avec;
#pragma unroll
    for (int i = 0; i < 8; i++) h[i] += bf2f(ap[i]);
  }

  float4 x0 = *(const float4*)&X[base];
  float4 x1 = *(const float4*)&X[base + 4];
  float xs[8] = {x0.x, x0.y, x0.z, x0.w, x1.x, x1.y, x1.z, x1.w};
#pragma unroll
  for (int i = 0; i < 8; i++) h[i] = h[i] * inv_l + xs[i];

  float sum = 0.f, sq = 0.f;
#pragma unroll
  for (int i = 0; i < 8; i++) { sum += h[i]; sq += h[i] * h[i]; }
#pragma unroll
  for (int d = 1; d < 64; d <<= 1) {
    sum += __shfl_xor(sum, d);
    sq  += __shfl_xor(sq, d);
  }
  float mu = sum * (1.f / 512.f);
  float var = sq * (1.f / 512.f) - mu * mu;
  float rstd = rsqrtf(var + LN_EPS);

  float4 g0 = *(const float4*)&gamma[lane * 8];
  float4 g1 = *(const float4*)&gamma[lane * 8 + 4];
  float4 b0 = *(const float4*)&beta[lane * 8];
  float4 b1 = *(const float4*)&beta[lane * 8 + 4];
  float gs[8] = {g0.x, g0.y, g0.z, g0.w, g1.x, g1.y, g1.z, g1.w};
  float bs[8] = {b0.x, b0.y, b0.z, b0.w, b1.x, b1.y, b1.z, b1.w};

  float4 o0, o1;
  float* op = (float*)&o0;
#pragma unroll
  for (int i = 0; i < 4; i++) op[i] = (h[i] - mu) * rstd * gs[i] + bs[i];
  float* op1 = (float*)&o1;
#pragma unroll
  for (int i = 0; i < 4; i++) op1[i] = (h[i + 4] - mu) * rstd * gs[i + 4] + bs[i + 4];
  *(float4*)&Out[base] = o0;
  *(float4*)&Out[base + 4] = o1;
}

// ---------------------------------------------------------------------------
extern "C" void kernel_launch(void* const* d_in, const int* in_sizes, int n_in,
                              void* d_out, int out_size, void* d_ws, size_t ws_size,
                              hipStream_t stream) {
  const float* x = (const float*)d_in[0];
  const float* Wq = (const float*)d_in[1];
  const float* Wk = (const float*)d_in[2];
  const float* Wv = (const float*)d_in[3];
  const float* gamma = (const float*)d_in[4];
  const float* beta = (const float*)d_in[5];

  char* ws = (char*)d_ws;
  u8*  Qws   = (u8*)(ws);                     // 8 MB fp8
  u8*  Kws   = (u8*)(ws + 8388608);           // 8 MB fp8
  u8*  Vt8ws = (u8*)(ws + 16777216);          // 8 MB fp8, [512][16384]
  u16* Wtws  = (u16*)(ws + 25165824);         // 1.5 MB bf16
  u16* Xbws  = (u16*)(ws + 26738688);         // 16 MB bf16 (dead after GEMM)
  u16* Opws  = (u16*)(ws + 26738688);         // 2 x 16 MB bf16 partials;
                                              //   slice 0 aliases Xb (safe:
                                              //   attn writes after gemm reads)
  const size_t PART = 16777216;
  float* Lws = (float*)(ws + 26738688 + 2 * PART);  // [4][16384] f32 = 256 KB

  hipLaunchKernelGGL(xcast_kernel, dim3(4096), dim3(256), 0, stream, x, Xbws);
  hipLaunchKernelGGL(transpose_w_kernel, dim3(1024, 3), dim3(256), 0, stream,
                     Wq, Wk, Wv, Wtws);
  hipLaunchKernelGGL(qkv_gemm_kernel, dim3(512, 3), dim3(256), 0, stream,
                     Xbws, Wtws, Qws, Kws, Vt8ws);
  hipLaunchKernelGGL(HIP_KERNEL_NAME(attn_partial_kernel<2>),
                     dim3(64, 4, 2), dim3(256), 0, stream,
                     Qws, Kws, Vt8ws, Opws, Lws);
  hipLaunchKernelGGL(HIP_KERNEL_NAME(combine_ln_kernel<2>),
                     dim3(4096), dim3(256), 0, stream,
                     Opws, Lws, x, gamma, beta, (float*)d_out);
}

// Round 6
// 268.546 us; speedup vs baseline: 1.1013x; 1.0694x over previous
//
#include <hip/hip_runtime.h>
#include <stdint.h>

typedef __attribute__((ext_vector_type(8))) __bf16 bf16x8;
typedef __attribute__((ext_vector_type(4))) float f32x4;
typedef __attribute__((ext_vector_type(16))) float f32x16;
typedef unsigned short u16;
typedef unsigned char u8;
typedef unsigned int u32;
typedef unsigned long long u64;
typedef long i64;

#define LN_EPS 1e-5f

__device__ __forceinline__ float bf2f(u16 u){
  union { u32 i; float f; } v; v.i = ((u32)u) << 16; return v.f;
}
__device__ __forceinline__ u16 f2bf(float f){
  union { float f; u32 i; } v; v.f = f;
  u32 u = v.i;
  u += 0x7fffu + ((u >> 16) & 1u);
  return (u16)(u >> 16);
}
// HW packed f32x2 -> 2x OCP e4m3 bytes (low word of dst). RNE + sat@448.
__device__ __forceinline__ u32 cvt_pk_fp8(float a, float b){
  u32 pk;
  asm("v_cvt_pk_fp8_f32 %0, %1, %2" : "=v"(pk) : "v"(a), "v"(b));
  return pk;   // byte0 = fp8(a), byte1 = fp8(b)
}

// Async global->LDS DMA, 16 B per lane (dest = uniform base + lane*16).
__device__ __forceinline__ void gload_lds16(const void* g, void* l) {
  __builtin_amdgcn_global_load_lds(
      (const __attribute__((address_space(1))) void*)g,
      (__attribute__((address_space(3))) void*)l, 16, 0, 0);
}

// ---------------------------------------------------------------------------
// Kernel 0: cast X f32 -> bf16 (one shot; kills 12x redundant conversion)
// ---------------------------------------------------------------------------
__global__ void xcast_kernel(const float* __restrict__ X, u16* __restrict__ Xb) {
  int idx = (blockIdx.x * 256 + threadIdx.x) * 8;
  float4 f0 = *(const float4*)&X[idx];
  float4 f1 = *(const float4*)&X[idx + 4];
  ushort4 lo, hi;
  lo.x = f2bf(f0.x); lo.y = f2bf(f0.y); lo.z = f2bf(f0.z); lo.w = f2bf(f0.w);
  hi.x = f2bf(f1.x); hi.y = f2bf(f1.y); hi.z = f2bf(f1.z); hi.w = f2bf(f1.w);
  *(ushort4*)&Xb[idx] = lo;
  *(ushort4*)&Xb[idx + 4] = hi;
}

// ---------------------------------------------------------------------------
// Kernel 1: transpose f32 weights -> Wt[3][512][512] bf16
// ---------------------------------------------------------------------------
__global__ void transpose_w_kernel(const float* __restrict__ Wq,
                                   const float* __restrict__ Wk,
                                   const float* __restrict__ Wv,
                                   u16* __restrict__ Wt) {
  const float* W = (blockIdx.y == 0) ? Wq : ((blockIdx.y == 1) ? Wk : Wv);
  u16* o = Wt + blockIdx.y * 512 * 512;
  int idx = blockIdx.x * 256 + threadIdx.x;
  int e = idx >> 9, d = idx & 511;
  o[e * 512 + d] = f2bf(W[d * 512 + e]);
}

// ---------------------------------------------------------------------------
// Kernel 2: QKV GEMM, fully DMA-staged (global_load_lds w=16 for A and B).
// As/Bs: 128 rows x 64 B, 16B granule g of row r stored at position g^(r&3).
// Q,K out fp8; V out fp8 TRANSPOSED Vt8[512][16384].
// r6 NEW: V epilogue goes through a padded LDS tile (Ls[e][tok], stride 144)
// and is written with coalesced 16B stores along the token dim.  The old
// uchar4-at-stride-16KB scatter had ~16x write amplification (64 distinct
// cache lines per store instr) on the whole 8 MB V tensor.
// ---------------------------------------------------------------------------
__launch_bounds__(256, 4)
__global__ void qkv_gemm_kernel(const u16* __restrict__ Xb,
                                const u16* __restrict__ Wt,
                                u8* __restrict__ Qo,
                                u8* __restrict__ Ko,
                                u8* __restrict__ Vto8) {
  const int z = blockIdx.y;
  const u16* Wtm = Wt + z * 512 * 512;
  const int mblk = blockIdx.x & 127;
  const int nblk = blockIdx.x >> 7;
  const int m0 = mblk * 128, n0 = nblk * 128;

  __shared__ __align__(16) u8 As[128 * 64];   // 8 KB
  __shared__ __align__(16) u8 Bs[128 * 64];   // 8 KB
  __shared__ __align__(16) u8 Ls[128 * 144];  // 18 KB, V epilogue transpose

  const int tid = threadIdx.x;
  const int lane = tid & 63, w = tid >> 6;
  const int wr = w >> 1, wc = w & 1;
  const int lrow = lane & 15, quad = lane >> 4;

  f32x4 acc[4][4];
#pragma unroll
  for (int i = 0; i < 4; i++)
#pragma unroll
    for (int j = 0; j < 4; j++) acc[i][j] = (f32x4){0.f, 0.f, 0.f, 0.f};

  const int srow = lane >> 2;          // 0..15 within run
  const int spos = lane & 3;           // granule position 0..3

  // preload k0 = 0
#pragma unroll
  for (int r2 = 0; r2 < 2; r2++) {
    int rowb = w * 32 + r2 * 16;
    int row = rowb + srow;
    int g = spos ^ (row & 3);
    gload_lds16(&Xb[(m0 + row) * 512 + g * 8], &As[rowb * 64]);
    gload_lds16(&Wtm[(n0 + row) * 512 + g * 8], &Bs[rowb * 64]);
  }

  for (int k = 0; k < 16; k++) {
    __syncthreads();   // tile-k DMAs complete (implicit vmcnt(0))
    bf16x8 a[4], b[4];
#pragma unroll
    for (int t = 0; t < 4; t++) {
      int ra = wr * 64 + t * 16 + lrow;
      a[t] = *(const bf16x8*)&As[ra * 64 + (quad ^ (ra & 3)) * 16];
      int rb = wc * 64 + t * 16 + lrow;
      b[t] = *(const bf16x8*)&Bs[rb * 64 + (quad ^ (rb & 3)) * 16];
    }
    __syncthreads();   // all waves' fragment reads done -> safe to restage
    if (k < 15) {
      int k0n = (k + 1) * 32;
#pragma unroll
      for (int r2 = 0; r2 < 2; r2++) {
        int rowb = w * 32 + r2 * 16;
        int row = rowb + srow;
        int g = spos ^ (row & 3);
        gload_lds16(&Xb[(m0 + row) * 512 + k0n + g * 8], &As[rowb * 64]);
        gload_lds16(&Wtm[(n0 + row) * 512 + k0n + g * 8], &Bs[rowb * 64]);
      }
    }
#pragma unroll
    for (int i = 0; i < 4; i++)
#pragma unroll
      for (int j = 0; j < 4; j++)
        acc[i][j] = __builtin_amdgcn_mfma_f32_16x16x32_bf16(a[i], b[j], acc[i][j], 0, 0, 0);
  }

  if (z < 2) {
    u8* O = (z == 0) ? Qo : Ko;
#pragma unroll
    for (int i = 0; i < 4; i++) {
      int rbase = m0 + wr * 64 + i * 16 + quad * 4;
#pragma unroll
      for (int j = 0; j < 4; j++) {
        int col = n0 + wc * 64 + j * 16 + lrow;
        u32 pk01 = cvt_pk_fp8(acc[i][j][0], acc[i][j][1]);
        u32 pk23 = cvt_pk_fp8(acc[i][j][2], acc[i][j][3]);
        O[(rbase + 0) * 512 + col] = (u8)pk01;
        O[(rbase + 1) * 512 + col] = (u8)(pk01 >> 8);
        O[(rbase + 2) * 512 + col] = (u8)pk23;
        O[(rbase + 3) * 512 + col] = (u8)(pk23 >> 8);
      }
    }
  } else {
    // ---- V: LDS transpose tile, then coalesced row stores ----
#pragma unroll
    for (int i = 0; i < 4; i++) {
      int tokb = wr * 64 + i * 16 + quad * 4;   // local token base (mult of 4)
#pragma unroll
      for (int j = 0; j < 4; j++) {
        int el = wc * 64 + j * 16 + lrow;       // local e (= d) index
        u32 pk01 = cvt_pk_fp8(acc[i][j][0], acc[i][j][1]);
        u32 pk23 = cvt_pk_fp8(acc[i][j][2], acc[i][j][3]);
        u32 pk = (pk01 & 0xffffu) | (pk23 << 16);
        *(u32*)&Ls[el * 144 + tokb] = pk;       // 4 tokens of column el
      }
    }
    __syncthreads();
    // Each instr: 8 e-rows x full 128 B token span -> 100% line efficiency.
#pragma unroll
    for (int k = 0; k < 4; k++) {
      int e = w * 32 + k * 8 + (lane >> 3);
      int tok = (lane & 7) * 16;
      uint4 vv = *(const uint4*)&Ls[e * 144 + tok];
      *(uint4*)&Vto8[(size_t)(n0 + e) * 16384 + m0 + tok] = vv;
    }
  }
}

// ---------------------------------------------------------------------------
// Kernel 3: flash attention partial, all-fp8 MFMA paths.
// ROUND-0 SCHEDULE (measured best: 153.5 us): single-buffer K/V,
// two __syncthreads per tile, K prefetch after barrier B, V prefetch after
// the wave-private lgkmcnt drain, PV via 32x32x16 fp8.
// Kept from later rounds: v_cvt_pk_fp8_f32 softmax pack (accuracy-positive,
// time-neutral per r3).  r1/r4/r5 structural variants all measured slower
// (160-172 us); occupancy is register-pinned at 2 waves/SIMD (128 AGPR acc),
// so this barrier schedule with cross-block phase overlap is the best known.
// ---------------------------------------------------------------------------
template <int NSPLIT>
__launch_bounds__(256, 2)
__global__ void attn_partial_kernel(const u8* __restrict__ Q,
                                    const u8* __restrict__ K,
                                    const u8* __restrict__ Vt8,
                                    u16* __restrict__ Opart,  // [NSPLIT][16384][512]
                                    float* __restrict__ L) {  // [NSPLIT][16384]
  constexpr int SPAN = 4096 / NSPLIT;   // keys per split
  constexpr int ITERS = SPAN / 32;      // 32-key tiles
  const int b = blockIdx.y;
  const int split = blockIdx.z;
  const int q0 = blockIdx.x * 64;
  const int tid = threadIdx.x;
  const int lane = tid & 63, w = tid >> 6;
  const int lrow = lane & 15, quad = lane >> 4;
  const int l31 = lane & 31, half = lane >> 5;

  __shared__ __align__(16) u8 Ks8[32 * 512];   // fp8, 16B-granule swizzle g^(row&7)
  __shared__ __align__(16) u8 Vs8[512 * 32];   // fp8, granule g16^((n>>2)&1)
  __shared__ __align__(16) u8 Pb8[64 * 40];    // fp8 P, row stride 40 B

  const int keybase = b * 4096 + split * SPAN;

  const int qtok = b * 4096 + q0 + w * 16 + lrow;
  i64 qf[16];
#pragma unroll
  for (int s = 0; s < 16; s++)
    qf[s] = *(const i64*)&Q[qtok * 512 + s * 32 + quad * 8];

  f32x16 Oacc[2][4];
#pragma unroll
  for (int i = 0; i < 2; i++)
#pragma unroll
    for (int j = 0; j < 4; j++)
#pragma unroll
      for (int e = 0; e < 16; e++) Oacc[i][j][e] = 0.f;

  float lsum[4] = {0.f, 0.f, 0.f, 0.f};
  const float scale = 0.044194173824159216f;  // 1/sqrt(512)

  // ---- preload tile 0 ----
#pragma unroll
  for (int i = 0; i < 4; i++) {       // K fp8: 8 rows/wave, 2 rows per run
    int row = w * 8 + i * 2 + (lane >> 5);
    int g = (lane & 31) ^ (row & 7);
    gload_lds16(&K[(keybase + row) * 512 + g * 16], &Ks8[(w * 8 + i * 2) * 512]);
  }
#pragma unroll
  for (int run = 0; run < 4; run++) { // V fp8: wave-private 128 rows, 32/run
    int rowb = w * 128 + run * 32;
    int n = rowb + (lane >> 1);
    int g16 = (lane & 1) ^ ((n >> 2) & 1);
    gload_lds16(&Vt8[n * 16384 + keybase + g16 * 16], &Vs8[rowb * 32]);
  }

  for (int it = 0; it < ITERS; ++it) {
    __syncthreads();  // tile-it DMAs done (implicit vmcnt(0)); Pb8(it-1) free

    // ---- QK^T (fp8) : S[16 rows][32 keys] per wave ----
    f32x4 S0 = {0.f, 0.f, 0.f, 0.f}, S1 = {0.f, 0.f, 0.f, 0.f};
#pragma unroll
    for (int s = 0; s < 16; s++) {
      int gs = (2 * s + (quad >> 1)) ^ (lrow & 7);
      int off = gs * 16 + (quad & 1) * 8;
      i64 k0 = *(const i64*)&Ks8[lrow * 512 + off];
      i64 k1 = *(const i64*)&Ks8[(16 + lrow) * 512 + off];
      S0 = __builtin_amdgcn_mfma_f32_16x16x32_fp8_fp8(qf[s], k0, S0, 0, 0, 0);
      S1 = __builtin_amdgcn_mfma_f32_16x16x32_fp8_fp8(qf[s], k1, S1, 0, 0, 0);
    }

    // ---- fixed-max softmax + write P as fp8 (HW packed convert) ----
#pragma unroll
    for (int r = 0; r < 4; r++) {
      float p0 = __expf(S0[r] * scale);
      float p1 = __expf(S1[r] * scale);
      lsum[r] += p0 + p1;
      u32 pk = cvt_pk_fp8(p0, p1);
      int prow = w * 16 + quad * 4 + r;
      Pb8[prow * 40 + lrow] = (u8)pk;
      Pb8[prow * 40 + 16 + lrow] = (u8)(pk >> 8);
    }

    __syncthreads();  // P visible; Ks fully consumed

    const int kknext = (it + 1) * 32;
    if (it < ITERS - 1) {    // prefetch K(it+1), flies during PV
#pragma unroll
      for (int i = 0; i < 4; i++) {
        int row = w * 8 + i * 2 + (lane >> 5);
        int g = (lane & 31) ^ (row & 7);
        gload_lds16(&K[(keybase + kknext + row) * 512 + g * 16],
                    &Ks8[(w * 8 + i * 2) * 512]);
      }
    }

    // ---- PV (fp8): hoist all fragment reads, drain, prefetch V, MFMA ----
    i64 af[2][2];
#pragma unroll
    for (int i = 0; i < 2; i++)
#pragma unroll
      for (int kg = 0; kg < 2; kg++)
        af[i][kg] = *(const i64*)&Pb8[(i * 32 + l31) * 40 + kg * 16 + half * 8];

    i64 bv[4][2];
#pragma unroll
    for (int j = 0; j < 4; j++) {
      int n = w * 128 + j * 32 + l31;
      int x = (n >> 2) & 1;
#pragma unroll
      for (int kg = 0; kg < 2; kg++)
        bv[j][kg] = *(const i64*)&Vs8[n * 32 + (kg ^ x) * 16 + half * 8];
    }

    asm volatile("s_waitcnt lgkmcnt(0)" ::: "memory");

    if (it < ITERS - 1) {    // prefetch V(it+1), wave-private slice
#pragma unroll
      for (int run = 0; run < 4; run++) {
        int rowb = w * 128 + run * 32;
        int n = rowb + (lane >> 1);
        int g16 = (lane & 1) ^ ((n >> 2) & 1);
        gload_lds16(&Vt8[n * 16384 + keybase + kknext + g16 * 16], &Vs8[rowb * 32]);
      }
    }

#pragma unroll
    for (int j = 0; j < 4; j++)
#pragma unroll
      for (int i = 0; i < 2; i++) {
        Oacc[i][j] = __builtin_amdgcn_mfma_f32_32x32x16_fp8_fp8(af[i][0], bv[j][0], Oacc[i][j], 0, 0, 0);
        Oacc[i][j] = __builtin_amdgcn_mfma_f32_32x32x16_fp8_fp8(af[i][1], bv[j][1], Oacc[i][j], 0, 0, 0);
      }
  }

  // ---- reduce l across the 16 key-lanes ----
#pragma unroll
  for (int r = 0; r < 4; r++) {
    float s = lsum[r];
    s += __shfl_xor(s, 1); s += __shfl_xor(s, 2);
    s += __shfl_xor(s, 4); s += __shfl_xor(s, 8);
    lsum[r] = s;
  }
  const int tokw = b * 4096 + q0 + w * 16 + quad * 4;
  if (lrow == 0) {
#pragma unroll
    for (int r = 0; r < 4; r++)
      L[split * 16384 + tokw + r] = lsum[r];
  }

  // ---- store unnormalized O partial, bf16 (32x32 C-layout) ----
  u16* Ob = Opart + (size_t)split * (16384u * 512u);
  const int tokbase = b * 4096 + q0;
#pragma unroll
  for (int i = 0; i < 2; i++)
#pragma unroll
    for (int j = 0; j < 4; j++) {
      int col = w * 128 + j * 32 + l31;
#pragma unroll
      for (int p = 0; p < 16; p++) {
        int row = i * 32 + (p & 3) + 8 * (p >> 2) + 4 * half;
        Ob[(tokbase + row) * 512 + col] = f2bf(Oacc[i][j][p]);
      }
    }
}

// ---------------------------------------------------------------------------
// Kernel 4: combine splits + residual + LayerNorm.  One wave per token.
// ---------------------------------------------------------------------------
template <int NSPLIT>
__launch_bounds__(256)
__global__ void combine_ln_kernel(const u16* __restrict__ Opart,
                                  const float* __restrict__ L,
                                  const float* __restrict__ X,
                                  const float* __restrict__ gamma,
                                  const float* __restrict__ beta,
                                  float* __restrict__ Out) {
  const int lane = threadIdx.x & 63;
  const int tok = blockIdx.x * 4 + (threadIdx.x >> 6);
  float lt = 0.f;
#pragma unroll
  for (int s = 0; s < NSPLIT; s++) lt += L[s * 16384 + tok];
  const float inv_l = 1.f / lt;
  const int base = tok * 512 + lane * 8;

  float h[8] = {0.f, 0.f, 0.f, 0.f, 0.f, 0.f, 0.f, 0.f};
#pragma unroll
  for (int s = 0; s < NSPLIT; s++) {
    uint4 avec = *(const uint4*)&Opart[(size_t)s * (16384u * 512u) + base];
    const u16* ap = (const u16*)&avec;
#pragma unroll
    for (int i = 0; i < 8; i++) h[i] += bf2f(ap[i]);
  }

  float4 x0 = *(const float4*)&X[base];
  float4 x1 = *(const float4*)&X[base + 4];
  float xs[8] = {x0.x, x0.y, x0.z, x0.w, x1.x, x1.y, x1.z, x1.w};
#pragma unroll
  for (int i = 0; i < 8; i++) h[i] = h[i] * inv_l + xs[i];

  float sum = 0.f, sq = 0.f;
#pragma unroll
  for (int i = 0; i < 8; i++) { sum += h[i]; sq += h[i] * h[i]; }
#pragma unroll
  for (int d = 1; d < 64; d <<= 1) {
    sum += __shfl_xor(sum, d);
    sq  += __shfl_xor(sq, d);
  }
  float mu = sum * (1.f / 512.f);
  float var = sq * (1.f / 512.f) - mu * mu;
  float rstd = rsqrtf(var + LN_EPS);

  float4 g0 = *(const float4*)&gamma[lane * 8];
  float4 g1 = *(const float4*)&gamma[lane * 8 + 4];
  float4 b0 = *(const float4*)&beta[lane * 8];
  float4 b1 = *(const float4*)&beta[lane * 8 + 4];
  float gs[8] = {g0.x, g0.y, g0.z, g0.w, g1.x, g1.y, g1.z, g1.w};
  float bs[8] = {b0.x, b0.y, b0.z, b0.w, b1.x, b1.y, b1.z, b1.w};

  float4 o0, o1;
  float* op = (float*)&o0;
#pragma unroll
  for (int i = 0; i < 4; i++) op[i] = (h[i] - mu) * rstd * gs[i] + bs[i];
  float* op1 = (float*)&o1;
#pragma unroll
  for (int i = 0; i < 4; i++) op1[i] = (h[i + 4] - mu) * rstd * gs[i + 4] + bs[i + 4];
  *(float4*)&Out[base] = o0;
  *(float4*)&Out[base + 4] = o1;
}

// ---------------------------------------------------------------------------
extern "C" void kernel_launch(void* const* d_in, const int* in_sizes, int n_in,
                              void* d_out, int out_size, void* d_ws, size_t ws_size,
                              hipStream_t stream) {
  const float* x = (const float*)d_in[0];
  const float* Wq = (const float*)d_in[1];
  const float* Wk = (const float*)d_in[2];
  const float* Wv = (const float*)d_in[3];
  const float* gamma = (const float*)d_in[4];
  const float* beta = (const float*)d_in[5];

  char* ws = (char*)d_ws;
  u8*  Qws   = (u8*)(ws);                     // 8 MB fp8
  u8*  Kws   = (u8*)(ws + 8388608);           // 8 MB fp8
  u8*  Vt8ws = (u8*)(ws + 16777216);          // 8 MB fp8, [512][16384]
  u16* Wtws  = (u16*)(ws + 25165824);         // 1.5 MB bf16
  u16* Xbws  = (u16*)(ws + 26738688);         // 16 MB bf16 (dead after GEMM)
  u16* Opws  = (u16*)(ws + 26738688);         // 2 x 16 MB bf16 partials;
                                              //   slice 0 aliases Xb (safe:
                                              //   attn writes after gemm reads)
  const size_t PART = 16777216;
  float* Lws = (float*)(ws + 26738688 + 2 * PART);  // [2][16384] f32

  hipLaunchKernelGGL(xcast_kernel, dim3(4096), dim3(256), 0, stream, x, Xbws);
  hipLaunchKernelGGL(transpose_w_kernel, dim3(1024, 3), dim3(256), 0, stream,
                     Wq, Wk, Wv, Wtws);
  hipLaunchKernelGGL(qkv_gemm_kernel, dim3(512, 3), dim3(256), 0, stream,
                     Xbws, Wtws, Qws, Kws, Vt8ws);
  hipLaunchKernelGGL(HIP_KERNEL_NAME(attn_partial_kernel<2>),
                     dim3(64, 4, 2), dim3(256), 0, stream,
                     Qws, Kws, Vt8ws, Opws, Lws);
  hipLaunchKernelGGL(HIP_KERNEL_NAME(combine_ln_kernel<2>),
                     dim3(4096), dim3(256), 0, stream,
                     Opws, Lws, x, gamma, beta, (float*)d_out);
}

// Round 7
// 267.017 us; speedup vs baseline: 1.1076x; 1.0057x over previous
//
#include <hip/hip_runtime.h>
#include <stdint.h>

typedef __attribute__((ext_vector_type(8))) __bf16 bf16x8;
typedef __attribute__((ext_vector_type(4))) float f32x4;
typedef __attribute__((ext_vector_type(16))) float f32x16;
typedef unsigned short u16;
typedef unsigned char u8;
typedef unsigned int u32;
typedef unsigned long long u64;
typedef long i64;

#define LN_EPS 1e-5f

__device__ __forceinline__ float bf2f(u16 u){
  union { u32 i; float f; } v; v.i = ((u32)u) << 16; return v.f;
}
__device__ __forceinline__ u16 f2bf(float f){
  union { float f; u32 i; } v; v.f = f;
  u32 u = v.i;
  u += 0x7fffu + ((u >> 16) & 1u);
  return (u16)(u >> 16);
}
// HW packed f32x2 -> 2x OCP e4m3 bytes (low word of dst). RNE + sat@448.
__device__ __forceinline__ u32 cvt_pk_fp8(float a, float b){
  u32 pk;
  asm("v_cvt_pk_fp8_f32 %0, %1, %2" : "=v"(pk) : "v"(a), "v"(b));
  return pk;   // byte0 = fp8(a), byte1 = fp8(b)
}

// Async global->LDS DMA, 16 B per lane (dest = uniform base + lane*16).
__device__ __forceinline__ void gload_lds16(const void* g, void* l) {
  __builtin_amdgcn_global_load_lds(
      (const __attribute__((address_space(1))) void*)g,
      (__attribute__((address_space(3))) void*)l, 16, 0, 0);
}

// ---------------------------------------------------------------------------
// Kernel 0: cast X f32 -> bf16 (one shot; kills 12x redundant conversion)
// ---------------------------------------------------------------------------
__global__ void xcast_kernel(const float* __restrict__ X, u16* __restrict__ Xb) {
  int idx = (blockIdx.x * 256 + threadIdx.x) * 8;
  float4 f0 = *(const float4*)&X[idx];
  float4 f1 = *(const float4*)&X[idx + 4];
  ushort4 lo, hi;
  lo.x = f2bf(f0.x); lo.y = f2bf(f0.y); lo.z = f2bf(f0.z); lo.w = f2bf(f0.w);
  hi.x = f2bf(f1.x); hi.y = f2bf(f1.y); hi.z = f2bf(f1.z); hi.w = f2bf(f1.w);
  *(ushort4*)&Xb[idx] = lo;
  *(ushort4*)&Xb[idx + 4] = hi;
}

// ---------------------------------------------------------------------------
// Kernel 1: transpose f32 weights -> Wt[3][512][512] bf16
// ---------------------------------------------------------------------------
__global__ void transpose_w_kernel(const float* __restrict__ Wq,
                                   const float* __restrict__ Wk,
                                   const float* __restrict__ Wv,
                                   u16* __restrict__ Wt) {
  const float* W = (blockIdx.y == 0) ? Wq : ((blockIdx.y == 1) ? Wk : Wv);
  u16* o = Wt + blockIdx.y * 512 * 512;
  int idx = blockIdx.x * 256 + threadIdx.x;
  int e = idx >> 9, d = idx & 511;
  o[e * 512 + d] = f2bf(W[d * 512 + e]);
}

// ---------------------------------------------------------------------------
// Kernel 2: QKV GEMM, fully DMA-staged (global_load_lds w=16 for A and B).
// As/Bs: 128 rows x 64 B, 16B granule g of row r stored at position g^(r&3).
// Q,K out fp8; V out fp8 TRANSPOSED Vt8[512][16384].
// V epilogue via padded LDS tile + coalesced 16B row stores (r6, verified
// win: killed ~16x write amplification of the uchar4 stride-16KB scatter).
// ---------------------------------------------------------------------------
__launch_bounds__(256, 4)
__global__ void qkv_gemm_kernel(const u16* __restrict__ Xb,
                                const u16* __restrict__ Wt,
                                u8* __restrict__ Qo,
                                u8* __restrict__ Ko,
                                u8* __restrict__ Vto8) {
  const int z = blockIdx.y;
  const u16* Wtm = Wt + z * 512 * 512;
  const int mblk = blockIdx.x & 127;
  const int nblk = blockIdx.x >> 7;
  const int m0 = mblk * 128, n0 = nblk * 128;

  __shared__ __align__(16) u8 As[128 * 64];   // 8 KB
  __shared__ __align__(16) u8 Bs[128 * 64];   // 8 KB
  __shared__ __align__(16) u8 Ls[128 * 144];  // 18 KB, V epilogue transpose

  const int tid = threadIdx.x;
  const int lane = tid & 63, w = tid >> 6;
  const int wr = w >> 1, wc = w & 1;
  const int lrow = lane & 15, quad = lane >> 4;

  f32x4 acc[4][4];
#pragma unroll
  for (int i = 0; i < 4; i++)
#pragma unroll
    for (int j = 0; j < 4; j++) acc[i][j] = (f32x4){0.f, 0.f, 0.f, 0.f};

  const int srow = lane >> 2;          // 0..15 within run
  const int spos = lane & 3;           // granule position 0..3

  // preload k0 = 0
#pragma unroll
  for (int r2 = 0; r2 < 2; r2++) {
    int rowb = w * 32 + r2 * 16;
    int row = rowb + srow;
    int g = spos ^ (row & 3);
    gload_lds16(&Xb[(m0 + row) * 512 + g * 8], &As[rowb * 64]);
    gload_lds16(&Wtm[(n0 + row) * 512 + g * 8], &Bs[rowb * 64]);
  }

  for (int k = 0; k < 16; k++) {
    __syncthreads();   // tile-k DMAs complete (implicit vmcnt(0))
    bf16x8 a[4], b[4];
#pragma unroll
    for (int t = 0; t < 4; t++) {
      int ra = wr * 64 + t * 16 + lrow;
      a[t] = *(const bf16x8*)&As[ra * 64 + (quad ^ (ra & 3)) * 16];
      int rb = wc * 64 + t * 16 + lrow;
      b[t] = *(const bf16x8*)&Bs[rb * 64 + (quad ^ (rb & 3)) * 16];
    }
    __syncthreads();   // all waves' fragment reads done -> safe to restage
    if (k < 15) {
      int k0n = (k + 1) * 32;
#pragma unroll
      for (int r2 = 0; r2 < 2; r2++) {
        int rowb = w * 32 + r2 * 16;
        int row = rowb + srow;
        int g = spos ^ (row & 3);
        gload_lds16(&Xb[(m0 + row) * 512 + k0n + g * 8], &As[rowb * 64]);
        gload_lds16(&Wtm[(n0 + row) * 512 + k0n + g * 8], &Bs[rowb * 64]);
      }
    }
#pragma unroll
    for (int i = 0; i < 4; i++)
#pragma unroll
      for (int j = 0; j < 4; j++)
        acc[i][j] = __builtin_amdgcn_mfma_f32_16x16x32_bf16(a[i], b[j], acc[i][j], 0, 0, 0);
  }

  if (z < 2) {
    u8* O = (z == 0) ? Qo : Ko;
#pragma unroll
    for (int i = 0; i < 4; i++) {
      int rbase = m0 + wr * 64 + i * 16 + quad * 4;
#pragma unroll
      for (int j = 0; j < 4; j++) {
        int col = n0 + wc * 64 + j * 16 + lrow;
        u32 pk01 = cvt_pk_fp8(acc[i][j][0], acc[i][j][1]);
        u32 pk23 = cvt_pk_fp8(acc[i][j][2], acc[i][j][3]);
        O[(rbase + 0) * 512 + col] = (u8)pk01;
        O[(rbase + 1) * 512 + col] = (u8)(pk01 >> 8);
        O[(rbase + 2) * 512 + col] = (u8)pk23;
        O[(rbase + 3) * 512 + col] = (u8)(pk23 >> 8);
      }
    }
  } else {
    // ---- V: LDS transpose tile, then coalesced row stores ----
#pragma unroll
    for (int i = 0; i < 4; i++) {
      int tokb = wr * 64 + i * 16 + quad * 4;   // local token base (mult of 4)
#pragma unroll
      for (int j = 0; j < 4; j++) {
        int el = wc * 64 + j * 16 + lrow;       // local e (= d) index
        u32 pk01 = cvt_pk_fp8(acc[i][j][0], acc[i][j][1]);
        u32 pk23 = cvt_pk_fp8(acc[i][j][2], acc[i][j][3]);
        u32 pk = (pk01 & 0xffffu) | (pk23 << 16);
        *(u32*)&Ls[el * 144 + tokb] = pk;       // 4 tokens of column el
      }
    }
    __syncthreads();
    // Each instr: 8 e-rows x full 128 B token span -> 100% line efficiency.
#pragma unroll
    for (int k = 0; k < 4; k++) {
      int e = w * 32 + k * 8 + (lane >> 3);
      int tok = (lane & 7) * 16;
      uint4 vv = *(const uint4*)&Ls[e * 144 + tok];
      *(uint4*)&Vto8[(size_t)(n0 + e) * 16384 + m0 + tok] = vv;
    }
  }
}

// ---------------------------------------------------------------------------
// Kernel 3: flash attention partial, all-fp8 MFMA paths.
// r7: KVBLK 32 -> 64 on the proven r0 schedule.  Same total MFMA work, half
// the iterations -> the ~2500-cycle/iter rendezvous overhead (2 barriers +
// drains + softmax issue) is paid 32x instead of 64x.
//   K: single 64x512 tile (32 KB), 4 QK row-groups (row&7 swizzle invariant
//      under +32/+48 offsets); prefetched after barrier B as before.
//   V/P: split in two 32-key buffers (Va/Vb, Pa/Pb) so each PV phase keeps
//      the r0 register footprint (af 8 + bv 16 VGPR) and its
//      read->drain->restage->MFMA overlap; Va restage flies under phase B.
// LDS 69 KB -> 2 blocks/CU (unchanged; occupancy is register-pinned anyway).
// ---------------------------------------------------------------------------
template <int NSPLIT>
__launch_bounds__(256, 2)
__global__ void attn_partial_kernel(const u8* __restrict__ Q,
                                    const u8* __restrict__ K,
                                    const u8* __restrict__ Vt8,
                                    u16* __restrict__ Opart,  // [NSPLIT][16384][512]
                                    float* __restrict__ L) {  // [NSPLIT][16384]
  constexpr int SPAN = 4096 / NSPLIT;   // keys per split
  constexpr int ITERS = SPAN / 64;      // 64-key tiles
  const int b = blockIdx.y;
  const int split = blockIdx.z;
  const int q0 = blockIdx.x * 64;
  const int tid = threadIdx.x;
  const int lane = tid & 63, w = tid >> 6;
  const int lrow = lane & 15, quad = lane >> 4;
  const int l31 = lane & 31, half = lane >> 5;

  __shared__ __align__(16) u8 Ks8[64 * 512];   // fp8, 16B-granule swz g^(row&7)
  __shared__ __align__(16) u8 Va8[512 * 32];   // fp8 V keys 0-31 of tile
  __shared__ __align__(16) u8 Vb8[512 * 32];   // fp8 V keys 32-63 of tile
  __shared__ __align__(16) u8 Pa8[64 * 40];    // fp8 P keys 0-31, stride 40
  __shared__ __align__(16) u8 Pb8[64 * 40];    // fp8 P keys 32-63

  const int keybase = b * 4096 + split * SPAN;

  const int qtok = b * 4096 + q0 + w * 16 + lrow;
  i64 qf[16];
#pragma unroll
  for (int s = 0; s < 16; s++)
    qf[s] = *(const i64*)&Q[qtok * 512 + s * 32 + quad * 8];

  f32x16 Oacc[2][4];
#pragma unroll
  for (int i = 0; i < 2; i++)
#pragma unroll
    for (int j = 0; j < 4; j++)
#pragma unroll
      for (int e = 0; e < 16; e++) Oacc[i][j][e] = 0.f;

  float lsum[4] = {0.f, 0.f, 0.f, 0.f};
  const float scale = 0.044194173824159216f;  // 1/sqrt(512)

  auto stageK = [&](int kk) {   // 64 rows x 512 B, 8 DMAs/wave
#pragma unroll
    for (int i = 0; i < 8; i++) {
      int rowb = w * 16 + i * 2;
      int row = rowb + (lane >> 5);
      int g = (lane & 31) ^ (row & 7);
      gload_lds16(&K[(keybase + kk + row) * 512 + g * 16], &Ks8[rowb * 512]);
    }
  };
  auto stageV = [&](int kk, u8* Vbuf) {  // 512 rows x 32 B, wave-private 128
#pragma unroll
    for (int run = 0; run < 4; run++) {
      int rowb = w * 128 + run * 32;
      int n = rowb + (lane >> 1);
      int g16 = (lane & 1) ^ ((n >> 2) & 1);
      gload_lds16(&Vt8[n * 16384 + keybase + kk + g16 * 16], &Vbuf[rowb * 32]);
    }
  };

  // ---- preload tile 0 ----
  stageK(0);
  stageV(0, Va8);
  stageV(32, Vb8);

  for (int it = 0; it < ITERS; ++it) {
    __syncthreads();  // tile-it DMAs done (implicit vmcnt(0)); P bufs free

    // ---- QK^T (fp8): S[16 q][64 keys] per wave, 4 key-row-groups ----
    f32x4 S0 = {0.f, 0.f, 0.f, 0.f}, S1 = {0.f, 0.f, 0.f, 0.f};
    f32x4 S2 = {0.f, 0.f, 0.f, 0.f}, S3 = {0.f, 0.f, 0.f, 0.f};
#pragma unroll
    for (int s = 0; s < 16; s++) {
      int gs = (2 * s + (quad >> 1)) ^ (lrow & 7);
      int off = gs * 16 + (quad & 1) * 8;
      i64 k0 = *(const i64*)&Ks8[lrow * 512 + off];
      i64 k1 = *(const i64*)&Ks8[(16 + lrow) * 512 + off];
      i64 k2 = *(const i64*)&Ks8[(32 + lrow) * 512 + off];
      i64 k3 = *(const i64*)&Ks8[(48 + lrow) * 512 + off];
      S0 = __builtin_amdgcn_mfma_f32_16x16x32_fp8_fp8(qf[s], k0, S0, 0, 0, 0);
      S1 = __builtin_amdgcn_mfma_f32_16x16x32_fp8_fp8(qf[s], k1, S1, 0, 0, 0);
      S2 = __builtin_amdgcn_mfma_f32_16x16x32_fp8_fp8(qf[s], k2, S2, 0, 0, 0);
      S3 = __builtin_amdgcn_mfma_f32_16x16x32_fp8_fp8(qf[s], k3, S3, 0, 0, 0);
    }

    // ---- fixed-max softmax + write P halves as fp8 ----
#pragma unroll
    for (int r = 0; r < 4; r++) {
      float p0 = __expf(S0[r] * scale);
      float p1 = __expf(S1[r] * scale);
      float p2 = __expf(S2[r] * scale);
      float p3 = __expf(S3[r] * scale);
      lsum[r] += (p0 + p1) + (p2 + p3);
      u32 pkA = cvt_pk_fp8(p0, p1);
      u32 pkB = cvt_pk_fp8(p2, p3);
      int prow = w * 16 + quad * 4 + r;
      Pa8[prow * 40 + lrow] = (u8)pkA;
      Pa8[prow * 40 + 16 + lrow] = (u8)(pkA >> 8);
      Pb8[prow * 40 + lrow] = (u8)pkB;
      Pb8[prow * 40 + 16 + lrow] = (u8)(pkB >> 8);
    }

    __syncthreads();  // P visible; Ks fully consumed

    const int kknext = (it + 1) * 64;
    if (it < ITERS - 1) stageK(kknext);   // flies during both PV phases

    // ---- PV phase A (keys 0-31): read frags, drain, restage Va, MFMA ----
    {
      i64 af[2][2];
#pragma unroll
      for (int i = 0; i < 2; i++)
#pragma unroll
        for (int kg = 0; kg < 2; kg++)
          af[i][kg] = *(const i64*)&Pa8[(i * 32 + l31) * 40 + kg * 16 + half * 8];
      i64 bv[4][2];
#pragma unroll
      for (int j = 0; j < 4; j++) {
        int n = w * 128 + j * 32 + l31;
        int x = (n >> 2) & 1;
#pragma unroll
        for (int kg = 0; kg < 2; kg++)
          bv[j][kg] = *(const i64*)&Va8[n * 32 + (kg ^ x) * 16 + half * 8];
      }
      asm volatile("s_waitcnt lgkmcnt(0)" ::: "memory");
      if (it < ITERS - 1) stageV(kknext, Va8);
#pragma unroll
      for (int j = 0; j < 4; j++)
#pragma unroll
        for (int i = 0; i < 2; i++) {
          Oacc[i][j] = __builtin_amdgcn_mfma_f32_32x32x16_fp8_fp8(af[i][0], bv[j][0], Oacc[i][j], 0, 0, 0);
          Oacc[i][j] = __builtin_amdgcn_mfma_f32_32x32x16_fp8_fp8(af[i][1], bv[j][1], Oacc[i][j], 0, 0, 0);
        }
    }

    // ---- PV phase B (keys 32-63) ----
    {
      i64 af[2][2];
#pragma unroll
      for (int i = 0; i < 2; i++)
#pragma unroll
        for (int kg = 0; kg < 2; kg++)
          af[i][kg] = *(const i64*)&Pb8[(i * 32 + l31) * 40 + kg * 16 + half * 8];
      i64 bv[4][2];
#pragma unroll
      for (int j = 0; j < 4; j++) {
        int n = w * 128 + j * 32 + l31;
        int x = (n >> 2) & 1;
#pragma unroll
        for (int kg = 0; kg < 2; kg++)
          bv[j][kg] = *(const i64*)&Vb8[n * 32 + (kg ^ x) * 16 + half * 8];
      }
      asm volatile("s_waitcnt lgkmcnt(0)" ::: "memory");
      if (it < ITERS - 1) stageV(kknext + 32, Vb8);
#pragma unroll
      for (int j = 0; j < 4; j++)
#pragma unroll
        for (int i = 0; i < 2; i++) {
          Oacc[i][j] = __builtin_amdgcn_mfma_f32_32x32x16_fp8_fp8(af[i][0], bv[j][0], Oacc[i][j], 0, 0, 0);
          Oacc[i][j] = __builtin_amdgcn_mfma_f32_32x32x16_fp8_fp8(af[i][1], bv[j][1], Oacc[i][j], 0, 0, 0);
        }
    }
  }

  // ---- reduce l across the 16 key-lanes ----
#pragma unroll
  for (int r = 0; r < 4; r++) {
    float s = lsum[r];
    s += __shfl_xor(s, 1); s += __shfl_xor(s, 2);
    s += __shfl_xor(s, 4); s += __shfl_xor(s, 8);
    lsum[r] = s;
  }
  const int tokw = b * 4096 + q0 + w * 16 + quad * 4;
  if (lrow == 0) {
#pragma unroll
    for (int r = 0; r < 4; r++)
      L[split * 16384 + tokw + r] = lsum[r];
  }

  // ---- store unnormalized O partial, bf16 (32x32 C-layout) ----
  u16* Ob = Opart + (size_t)split * (16384u * 512u);
  const int tokbase = b * 4096 + q0;
#pragma unroll
  for (int i = 0; i < 2; i++)
#pragma unroll
    for (int j = 0; j < 4; j++) {
      int col = w * 128 + j * 32 + l31;
#pragma unroll
      for (int p = 0; p < 16; p++) {
        int row = i * 32 + (p & 3) + 8 * (p >> 2) + 4 * half;
        Ob[(tokbase + row) * 512 + col] = f2bf(Oacc[i][j][p]);
      }
    }
}

// ---------------------------------------------------------------------------
// Kernel 4: combine splits + residual + LayerNorm.  One wave per token.
// ---------------------------------------------------------------------------
template <int NSPLIT>
__launch_bounds__(256)
__global__ void combine_ln_kernel(const u16* __restrict__ Opart,
                                  const float* __restrict__ L,
                                  const float* __restrict__ X,
                                  const float* __restrict__ gamma,
                                  const float* __restrict__ beta,
                                  float* __restrict__ Out) {
  const int lane = threadIdx.x & 63;
  const int tok = blockIdx.x * 4 + (threadIdx.x >> 6);
  float lt = 0.f;
#pragma unroll
  for (int s = 0; s < NSPLIT; s++) lt += L[s * 16384 + tok];
  const float inv_l = 1.f / lt;
  const int base = tok * 512 + lane * 8;

  float h[8] = {0.f, 0.f, 0.f, 0.f, 0.f, 0.f, 0.f, 0.f};
#pragma unroll
  for (int s = 0; s < NSPLIT; s++) {
    uint4 avec = *(const uint4*)&Opart[(size_t)s * (16384u * 512u) + base];
    const u16* ap = (const u16*)&avec;
#pragma unroll
    for (int i = 0; i < 8; i++) h[i] += bf2f(ap[i]);
  }

  float4 x0 = *(const float4*)&X[base];
  float4 x1 = *(const float4*)&X[base + 4];
  float xs[8] = {x0.x, x0.y, x0.z, x0.w, x1.x, x1.y, x1.z, x1.w};
#pragma unroll
  for (int i = 0; i < 8; i++) h[i] = h[i] * inv_l + xs[i];

  float sum = 0.f, sq = 0.f;
#pragma unroll
  for (int i = 0; i < 8; i++) { sum += h[i]; sq += h[i] * h[i]; }
#pragma unroll
  for (int d = 1; d < 64; d <<= 1) {
    sum += __shfl_xor(sum, d);
    sq  += __shfl_xor(sq, d);
  }
  float mu = sum * (1.f / 512.f);
  float var = sq * (1.f / 512.f) - mu * mu;
  float rstd = rsqrtf(var + LN_EPS);

  float4 g0 = *(const float4*)&gamma[lane * 8];
  float4 g1 = *(const float4*)&gamma[lane * 8 + 4];
  float4 b0 = *(const float4*)&beta[lane * 8];
  float4 b1 = *(const float4*)&beta[lane * 8 + 4];
  float gs[8] = {g0.x, g0.y, g0.z, g0.w, g1.x, g1.y, g1.z, g1.w};
  float bs[8] = {b0.x, b0.y, b0.z, b0.w, b1.x, b1.y, b1.z, b1.w};

  float4 o0, o1;
  float* op = (float*)&o0;
#pragma unroll
  for (int i = 0; i < 4; i++) op[i] = (h[i] - mu) * rstd * gs[i] + bs[i];
  float* op1 = (float*)&o1;
#pragma unroll
  for (int i = 0; i < 4; i++) op1[i] = (h[i + 4] - mu) * rstd * gs[i + 4] + bs[i + 4];
  *(float4*)&Out[base] = o0;
  *(float4*)&Out[base + 4] = o1;
}

// ---------------------------------------------------------------------------
extern "C" void kernel_launch(void* const* d_in, const int* in_sizes, int n_in,
                              void* d_out, int out_size, void* d_ws, size_t ws_size,
                              hipStream_t stream) {
  const float* x = (const float*)d_in[0];
  const float* Wq = (const float*)d_in[1];
  const float* Wk = (const float*)d_in[2];
  const float* Wv = (const float*)d_in[3];
  const float* gamma = (const float*)d_in[4];
  const float* beta = (const float*)d_in[5];

  char* ws = (char*)d_ws;
  u8*  Qws   = (u8*)(ws);                     // 8 MB fp8
  u8*  Kws   = (u8*)(ws + 8388608);           // 8 MB fp8
  u8*  Vt8ws = (u8*)(ws + 16777216);          // 8 MB fp8, [512][16384]
  u16* Wtws  = (u16*)(ws + 25165824);         // 1.5 MB bf16
  u16* Xbws  = (u16*)(ws + 26738688);         // 16 MB bf16 (dead after GEMM)
  u16* Opws  = (u16*)(ws + 26738688);         // 2 x 16 MB bf16 partials;
                                              //   slice 0 aliases Xb (safe:
                                              //   attn writes after gemm reads)
  const size_t PART = 16777216;
  float* Lws = (float*)(ws + 26738688 + 2 * PART);  // [2][16384] f32

  hipLaunchKernelGGL(xcast_kernel, dim3(4096), dim3(256), 0, stream, x, Xbws);
  hipLaunchKernelGGL(transpose_w_kernel, dim3(1024, 3), dim3(256), 0, stream,
                     Wq, Wk, Wv, Wtws);
  hipLaunchKernelGGL(qkv_gemm_kernel, dim3(512, 3), dim3(256), 0, stream,
                     Xbws, Wtws, Qws, Kws, Vt8ws);
  hipLaunchKernelGGL(HIP_KERNEL_NAME(attn_partial_kernel<2>),
                     dim3(64, 4, 2), dim3(256), 0, stream,
                     Qws, Kws, Vt8ws, Opws, Lws);
  hipLaunchKernelGGL(HIP_KERNEL_NAME(combine_ln_kernel<2>),
                     dim3(4096), dim3(256), 0, stream,
                     Opws, Lws, x, gamma, beta, (float*)d_out);
}